// Round 17
// baseline (454.101 us; speedup 1.0000x reference)
//
#include <hip/hip_runtime.h>
#include <hip/hip_bf16.h>
#include <stdint.h>

#define B_SZ 4
#define H_N 8
#define S_LEN 2048
#define D_HEAD 256
#define HD 2048

typedef __attribute__((ext_vector_type(8))) short bf16x8;
typedef __attribute__((ext_vector_type(4))) float f32x4;
typedef __attribute__((ext_vector_type(4))) uint32_t u32x4;
typedef __hip_bfloat16 bf16;

typedef __attribute__((address_space(1))) const void glob_cv;
typedef __attribute__((address_space(3))) void lds_v;

__device__ __forceinline__ short f2bf(float f) {
  bf16 h = __float2bfloat16(f);
  return *reinterpret_cast<short*>(&h);
}

__device__ __forceinline__ uint32_t cvtpk(float lo, float hi) {
  uint32_t r;
  asm volatile("v_cvt_pk_bf16_f32 %0, %1, %2" : "=v"(r) : "v"(lo), "v"(hi));
  return r;
}

// ---------------- fused f32 -> bf16 converts (7 buffers, 1 launch) ----------------
__global__ __launch_bounds__(256) void cvt_all(
    const float* __restrict__ w0, bf16* __restrict__ o0,
    const float* __restrict__ w1, bf16* __restrict__ o1,
    const float* __restrict__ w2, bf16* __restrict__ o2,
    const float* __restrict__ w3, bf16* __restrict__ o3,
    const float* __restrict__ x0, bf16* __restrict__ y0,
    const float* __restrict__ x1, bf16* __restrict__ y1,
    const float* __restrict__ x2, bf16* __restrict__ y2) {
  int bid = blockIdx.x;
  const float* src; bf16* dst; int off;
  if (bid < 1024) {
    int k = bid >> 8; off = (bid & 255) * 2048;
    src = k == 0 ? w0 : k == 1 ? w1 : k == 2 ? w2 : w3;
    dst = k == 0 ? o0 : k == 1 ? o1 : k == 2 ? o2 : o3;
  } else {
    int j = bid - 1024; int k = j >> 10; off = (j & 1023) * 2048;
    src = k == 0 ? x0 : k == 1 ? x1 : x2;
    dst = k == 0 ? y0 : k == 1 ? y1 : y2;
  }
  int i = off + threadIdx.x * 8;
  float4 a = *(const float4*)(src + i);
  float4 b = *(const float4*)(src + i + 4);
  bf16x8 o;
  o[0] = f2bf(a.x); o[1] = f2bf(a.y); o[2] = f2bf(a.z); o[3] = f2bf(a.w);
  o[4] = f2bf(b.x); o[5] = f2bf(b.y); o[6] = f2bf(b.z); o[7] = f2bf(b.w);
  *reinterpret_cast<bf16x8*>(dst + i) = o;
}

// ---------------- merged projection GEMM: 3 GEMMs in one dispatch ----------------
__global__ __launch_bounds__(256, 2) void proj3(
    const bf16* __restrict__ A0, const bf16* __restrict__ A1, const bf16* __restrict__ A2,
    const bf16* __restrict__ B0, const bf16* __restrict__ B1, const bf16* __restrict__ B2,
    const float* __restrict__ c0, const float* __restrict__ c1, const float* __restrict__ c2,
    bf16* __restrict__ O0, bf16* __restrict__ O1, bf16* __restrict__ O2) {
  constexpr int HALF = 2 * 128 * 128;
  __shared__ __align__(16) char lds[2 * HALF];

  int which = blockIdx.y;
  const bf16* A = which == 0 ? A0 : which == 1 ? A1 : A2;
  const bf16* Bm = which == 0 ? B0 : which == 1 ? B1 : B2;
  const float* bias = which == 0 ? c0 : which == 1 ? c1 : c2;
  bf16* OutP = which == 0 ? O0 : which == 1 ? O1 : O2;
  float scale = which == 0 ? (1.0f / 16.0f) * 1.44269504f : 1.0f;

  int tid = threadIdx.x;
  int w = tid >> 6, l = tid & 63;
  int l15 = l & 15, lg = l >> 4;
  int wr = w >> 1, wc = w & 1;

  int bid = blockIdx.x;
  int wg = (bid & 7) * 128 + (bid >> 3);
  int mt = wg >> 4, nt = wg & 15;
  int m0 = mt * 128, n0 = nt * 128;

  const size_t K2 = 512;
  char* ldsp = (char*)lds;
  const char* Abase = (const char*)A + (size_t)m0 * K2;
  const char* Bbase = (const char*)Bm + (size_t)n0 * K2;

  auto ISSUE = [&](int buf, int kt) {
    const char* As = Abase + (size_t)kt * 128;
    const char* Bs = Bbase + (size_t)kt * 128;
    char* db = ldsp + buf * HALF;
#pragma unroll
    for (int i = 0; i < 4; ++i) {
      int c = tid + i * 256, row = c >> 3;
      __builtin_amdgcn_global_load_lds((glob_cv*)(As + (size_t)row * K2 + 16 * ((c & 7) ^ (row & 7))),
                                       (lds_v*)(db + c * 16), 16, 0, 0);
    }
#pragma unroll
    for (int i = 0; i < 4; ++i) {
      int c = tid + i * 256, row = c >> 3;
      __builtin_amdgcn_global_load_lds((glob_cv*)(Bs + (size_t)row * K2 + 16 * ((c & 7) ^ (row & 7))),
                                       (lds_v*)(db + 16384 + c * 16), 16, 0, 0);
    }
  };

  f32x4 acc[4][4];
#pragma unroll
  for (int mi = 0; mi < 4; ++mi)
#pragma unroll
    for (int ni = 0; ni < 4; ++ni) acc[mi][ni] = f32x4{0.f, 0.f, 0.f, 0.f};

  ISSUE(0, 0);
  for (int kt = 0; kt < 4; ++kt) {
    int cur = kt & 1;
    if (kt < 3) {
      ISSUE(cur ^ 1, kt + 1);
      asm volatile("s_waitcnt vmcnt(8)" ::: "memory");
    } else {
      asm volatile("s_waitcnt vmcnt(0)" ::: "memory");
    }
    __builtin_amdgcn_s_barrier();
    __builtin_amdgcn_sched_barrier(0);

    const char* bufc = ldsp + cur * HALF;
#pragma unroll
    for (int kb2 = 0; kb2 < 2; ++kb2) {
      int swz = 16 * ((kb2 * 4 + lg) ^ (l15 & 7));
      bf16x8 af[4], bfr[4];
#pragma unroll
      for (int mi = 0; mi < 4; ++mi)
        af[mi] = *(const bf16x8*)(bufc + (wr * 64 + mi * 16 + l15) * 128 + swz);
#pragma unroll
      for (int ni = 0; ni < 4; ++ni)
        bfr[ni] = *(const bf16x8*)(bufc + 16384 + (wc * 64 + ni * 16 + l15) * 128 + swz);
#pragma unroll
      for (int mi = 0; mi < 4; ++mi)
#pragma unroll
        for (int ni = 0; ni < 4; ++ni)
          acc[mi][ni] = __builtin_amdgcn_mfma_f32_16x16x32_bf16(af[mi], bfr[ni], acc[mi][ni], 0, 0, 0);
    }
    __builtin_amdgcn_sched_barrier(0);
    __builtin_amdgcn_s_barrier();
  }

  if (which == 2) {
    // V epilogue: LDS transpose -> coalesced stores into Vt[bh][d][j]
    bf16* tp = (bf16*)lds;
#pragma unroll
    for (int ni = 0; ni < 4; ++ni) {
      int colL = wc * 64 + ni * 16 + l15;
      float bv = bias[n0 + colL];
#pragma unroll
      for (int mi = 0; mi < 4; ++mi) {
        short4 pk4;
        pk4.x = f2bf(acc[mi][ni][0] + bv);
        pk4.y = f2bf(acc[mi][ni][1] + bv);
        pk4.z = f2bf(acc[mi][ni][2] + bv);
        pk4.w = f2bf(acc[mi][ni][3] + bv);
        *(short4*)(tp + colL * 136 + wr * 64 + mi * 16 + lg * 4) = pk4;
      }
    }
    __syncthreads();
    int b = m0 >> 11, h = (m0 >> 8) & 7;
    int ehi = n0 >> 8, t0 = m0 & 255;
    bf16* vb = OutP + (size_t)(b * 8 + h) * D_HEAD * S_LEN;
#pragma unroll
    for (int p = 0; p < 8; ++p) {
      int colL = p * 16 + (tid >> 4);
      int d = (n0 & 255) + colL;
      int4 v = *(const int4*)(tp + colL * 136 + (tid & 15) * 8);
      *(int4*)(vb + (size_t)d * S_LEN + ehi * 256 + t0 + (tid & 15) * 8) = v;
    }
  } else {
#pragma unroll
    for (int ni = 0; ni < 4; ++ni) {
      int col = n0 + wc * 64 + ni * 16 + l15;
      float bv = bias[col];
#pragma unroll
      for (int mi = 0; mi < 4; ++mi) {
#pragma unroll
        for (int r = 0; r < 4; ++r) {
          float v = (acc[mi][ni][r] + bv) * scale;
          int row = m0 + wr * 64 + mi * 16 + lg * 4 + r;
          int b = row >> 11;
          int h = (row >> 8) & 7;
          int d = col & 255;
          size_t off;
          if (which == 1) {
            int jj = (col >> 8) * 256 + (row & 255);            // kv-permuted K rows
            off = (((size_t)(b * 8 + h) * S_LEN) + jj) * D_HEAD + d;
          } else {
            int sp = ((row & 255) << 3) | (col >> 8);           // Q keeps sp order
            off = (((size_t)(b * 8 + h) * S_LEN) + sp) * D_HEAD + d;
          }
          OutP[off] = __float2bfloat16(v);
        }
      }
    }
  }
}

// ---------------- output GEMM: 64x64 tile, K=2048, 512 blocks ----------------
__global__ __launch_bounds__(256, 2) void out_gemm(const bf16* __restrict__ A,
                                                   const bf16* __restrict__ Bm,
                                                   const float* __restrict__ bias,
                                                   float* __restrict__ Out) {
  constexpr int HALF = 2 * 64 * 128;
  __shared__ __align__(16) char lds[2 * HALF];

  int tid = threadIdx.x;
  int w = tid >> 6, l = tid & 63;
  int l15 = l & 15, lg = l >> 4;
  int wr = w >> 1, wc = w & 1;

  int bid = blockIdx.x;
  int wg = (bid & 7) * 64 + (bid >> 3);
  int mt = wg >> 2, nt = wg & 3;
  int m0 = mt * 64, n0 = nt * 64;

  const size_t K2 = 4096;
  char* ldsp = (char*)lds;
  const char* Abase = (const char*)A + (size_t)m0 * K2;
  const char* Bbase = (const char*)Bm + (size_t)n0 * K2;

  auto ISSUE = [&](int buf, int kt) {
    const char* As = Abase + (size_t)kt * 128;
    const char* Bs = Bbase + (size_t)kt * 128;
    char* db = ldsp + buf * HALF;
#pragma unroll
    for (int i = 0; i < 2; ++i) {
      int c = tid + i * 256, row = c >> 3;
      __builtin_amdgcn_global_load_lds((glob_cv*)(As + (size_t)row * K2 + 16 * ((c & 7) ^ (row & 7))),
                                       (lds_v*)(db + c * 16), 16, 0, 0);
    }
#pragma unroll
    for (int i = 0; i < 2; ++i) {
      int c = tid + i * 256, row = c >> 3;
      __builtin_amdgcn_global_load_lds((glob_cv*)(Bs + (size_t)row * K2 + 16 * ((c & 7) ^ (row & 7))),
                                       (lds_v*)(db + 8192 + c * 16), 16, 0, 0);
    }
  };

  f32x4 acc[2][2];
#pragma unroll
  for (int mi = 0; mi < 2; ++mi)
#pragma unroll
    for (int ni = 0; ni < 2; ++ni) acc[mi][ni] = f32x4{0.f, 0.f, 0.f, 0.f};

  ISSUE(0, 0);
  for (int kt = 0; kt < 32; ++kt) {
    int cur = kt & 1;
    if (kt < 31) {
      ISSUE(cur ^ 1, kt + 1);
      asm volatile("s_waitcnt vmcnt(4)" ::: "memory");
    } else {
      asm volatile("s_waitcnt vmcnt(0)" ::: "memory");
    }
    __builtin_amdgcn_s_barrier();
    __builtin_amdgcn_sched_barrier(0);

    const char* bufc = ldsp + cur * HALF;
#pragma unroll
    for (int kb2 = 0; kb2 < 2; ++kb2) {
      int swz = 16 * ((kb2 * 4 + lg) ^ (l15 & 7));
      bf16x8 af[2], bfr[2];
#pragma unroll
      for (int mi = 0; mi < 2; ++mi)
        af[mi] = *(const bf16x8*)(bufc + (wr * 32 + mi * 16 + l15) * 128 + swz);
#pragma unroll
      for (int ni = 0; ni < 2; ++ni)
        bfr[ni] = *(const bf16x8*)(bufc + 8192 + (wc * 32 + ni * 16 + l15) * 128 + swz);
#pragma unroll
      for (int mi = 0; mi < 2; ++mi)
#pragma unroll
        for (int ni = 0; ni < 2; ++ni)
          acc[mi][ni] = __builtin_amdgcn_mfma_f32_16x16x32_bf16(af[mi], bfr[ni], acc[mi][ni], 0, 0, 0);
    }
    __builtin_amdgcn_sched_barrier(0);
    __builtin_amdgcn_s_barrier();
  }

#pragma unroll
  for (int ni = 0; ni < 2; ++ni) {
    int col = n0 + wc * 32 + ni * 16 + l15;
    float bv = bias[col];
#pragma unroll
    for (int mi = 0; mi < 2; ++mi)
#pragma unroll
      for (int r = 0; r < 4; ++r)
        Out[(size_t)(m0 + wr * 32 + mi * 16 + lg * 4 + r) * 256 + col] = acc[mi][ni][r] + bv;
  }
}

// ---------------- flash attention ----------------
// 512 blocks x 256 threads: 4 waves x 32 q-rows (2 subtiles), static softmax.
// CROSS-TILE PIPELINE (R17): iteration t runs QK(t) and PV(t-1) as independent
// MFMA streams (P held in registers). K double-buffered (16KB x2), V TRIPLE-
// buffered (16KB x3, PV(t-1) reads buf[(t-1)%3] while ISSUE writes buf[(t+1)%3])
// -> 80 KB LDS, still 2 blocks/CU. Single barrier/iter; loads issued one full
// iteration ahead.
__global__ __launch_bounds__(256, 2) void attn_kernel(const bf16* __restrict__ Qp,
                                                      const bf16* __restrict__ Kp,
                                                      const bf16* __restrict__ Vt,
                                                      bf16* __restrict__ AL) {
  __shared__ __align__(16) bf16 KVs[5 * 8192];    // K: [0,16384)elems x2; V: [16384,40960) x3

  int tid = threadIdx.x;
  int w = tid >> 6, l = tid & 63;
  int l15 = l & 15, lg = l >> 4;
  int l31 = l & 31, hl = l >> 5;

  int bid = blockIdx.x;
  int xcd = bid & 7, j = bid >> 3;
  int bh = xcd + 8 * (j >> 4);
  int qt = j & 15;

  const bf16* Qb = Qp + (size_t)bh * S_LEN * D_HEAD;
  const bf16* Kb = Kp + (size_t)bh * S_LEN * D_HEAD;
  const bf16* Vb = Vt + (size_t)bh * (size_t)D_HEAD * S_LEN;

  int q0 = qt * 128 + w * 32;

  bf16x8 qf0[8], qf1[8];
#pragma unroll
  for (int kb = 0; kb < 8; ++kb) {
    qf0[kb] = *(const bf16x8*)(Qb + (size_t)(q0 + l15) * D_HEAD + kb * 32 + lg * 8);
    qf1[kb] = *(const bf16x8*)(Qb + (size_t)(q0 + 16 + l15) * D_HEAD + kb * 32 + lg * 8);
  }

  f32x4 acc0[16], acc1[16];
#pragma unroll
  for (int n = 0; n < 16; ++n) {
    acc0[n] = f32x4{0.f, 0.f, 0.f, 0.f};
    acc1[n] = f32x4{0.f, 0.f, 0.f, 0.f};
  }
  float lp0 = 0.f, lp1 = 0.f;

  int kvp = 2 * (l31 & 15) + (l31 >> 4);
  const char* pK = (const char*)Kb + (size_t)kvp * 512 + (size_t)(w * 256 + hl * 16);
  const char* pV = (const char*)Vb + (size_t)l * 4096 + (size_t)((w - 2) * 32);
  int dK = w * 8192 + l * 16;          // byte offset within one K buffer (16 KB)
  int dV = (w - 2) * 8192 + l * 16;    // byte offset within one V buffer (16 KB)
  char* ldsBase = (char*)&KVs[0];

  auto ISSUE = [&](int kbuf, int vbuf) {
    if (w < 2) {
      char* bb = ldsBase + kbuf * 16384;
#pragma unroll
      for (int i = 0; i < 8; ++i)
        __builtin_amdgcn_global_load_lds((glob_cv*)(pK + i * 32),
                                         (lds_v*)(bb + dK + i * 1024), 16, 0, 0);
      pK += 32 * 512;
    } else {
      char* bb = ldsBase + 32768 + vbuf * 16384;
#pragma unroll
      for (int i = 0; i < 8; ++i)
        __builtin_amdgcn_global_load_lds((glob_cv*)(pV + (i & 3) * 262144 + (i >> 2) * 16),
                                         (lds_v*)(bb + dV + (i & 3) * 1024 + (i >> 2) * 4096), 16, 0, 0);
      pV += 64;
    }
  };

  int krd = lg * 256 + l15 * 8;        // elem offset within K buffer
  int vrd = lg * 2048 + l15 * 8;       // elem offset within V buffer

  ISSUE(0, 0);                         // tile 0 -> K buf 0, V buf 0

  bf16x8 paP0{}, paP1{};               // P of previous tile (regs)
  int vPrev = 0, vThis = 0;

  for (int kt = 0; kt < 64; ++kt) {
    int kcur = kt & 1;
    asm volatile("s_waitcnt vmcnt(0)" ::: "memory");
    __builtin_amdgcn_s_barrier();      // tile kt landed; all waves past tile kt-1 reads
    __builtin_amdgcn_sched_barrier(0);
    int vNext = vThis + 1 == 3 ? 0 : vThis + 1;
    if (kt < 63) ISSUE(kcur ^ 1, vNext);

    const bf16* Kt = (const bf16*)ldsBase + kcur * 8192;
    const bf16* Vp = (const bf16*)ldsBase + 16384 + vPrev * 8192;

    __builtin_amdgcn_s_setprio(1);
    // ---- QK^T(kt): swapped, 8-deep chains (R15 form) ----
    f32x4 s00 = f32x4{0.f,0.f,0.f,0.f}, s01 = f32x4{0.f,0.f,0.f,0.f};
    f32x4 s10 = f32x4{0.f,0.f,0.f,0.f}, s11 = f32x4{0.f,0.f,0.f,0.f};
#pragma unroll
    for (int kb = 0; kb < 8; ++kb) {
      bf16x8 kf0 = *(const bf16x8*)(Kt + krd + kb * 1024);
      bf16x8 kf1 = *(const bf16x8*)(Kt + krd + kb * 1024 + 128);
      s00 = __builtin_amdgcn_mfma_f32_16x16x32_bf16(kf0, qf0[kb], s00, 0, 0, 0);
      s01 = __builtin_amdgcn_mfma_f32_16x16x32_bf16(kf1, qf0[kb], s01, 0, 0, 0);
      s10 = __builtin_amdgcn_mfma_f32_16x16x32_bf16(kf0, qf1[kb], s10, 0, 0, 0);
      s11 = __builtin_amdgcn_mfma_f32_16x16x32_bf16(kf1, qf1[kb], s11, 0, 0, 0);
    }

    // ---- PV(kt-1): independent MFMA stream, V from old buffer, P in regs ----
    if (kt > 0) {
#pragma unroll
      for (int n = 0; n < 16; ++n) {
        bf16x8 vbf = *(const bf16x8*)(Vp + vrd + n * 128);
        acc0[n] = __builtin_amdgcn_mfma_f32_16x16x32_bf16(paP0, vbf, acc0[n], 0, 0, 0);
        acc1[n] = __builtin_amdgcn_mfma_f32_16x16x32_bf16(paP1, vbf, acc1[n], 0, 0, 0);
      }
    }
    __builtin_amdgcn_s_setprio(0);

    // ---- static softmax(kt) -> P regs for next iteration ----
    float p00[4], p01[4], p10[4], p11[4];
#pragma unroll
    for (int r = 0; r < 4; ++r) {
      p00[r] = exp2f(s00[r]); p01[r] = exp2f(s01[r]);
      p10[r] = exp2f(s10[r]); p11[r] = exp2f(s11[r]);
    }
    lp0 += (p00[0] + p01[0]) + (p00[1] + p01[1]) + (p00[2] + p01[2]) + (p00[3] + p01[3]);
    lp1 += (p10[0] + p11[0]) + (p10[1] + p11[1]) + (p10[2] + p11[2]) + (p10[3] + p11[3]);

    union { u32x4 wq; bf16x8 v; } pu0, pu1;
    pu0.wq[0] = cvtpk(p00[0], p01[0]); pu0.wq[1] = cvtpk(p00[1], p01[1]);
    pu0.wq[2] = cvtpk(p00[2], p01[2]); pu0.wq[3] = cvtpk(p00[3], p01[3]);
    pu1.wq[0] = cvtpk(p10[0], p11[0]); pu1.wq[1] = cvtpk(p10[1], p11[1]);
    pu1.wq[2] = cvtpk(p10[2], p11[2]); pu1.wq[3] = cvtpk(p10[3], p11[3]);
    paP0 = pu0.v; paP1 = pu1.v;

    vPrev = vThis; vThis = vNext;
  }

  // ---- final PV for tile 63 (buffer vPrev; no overwrite possible) ----
  {
    const bf16* Vp = (const bf16*)ldsBase + 16384 + vPrev * 8192;
#pragma unroll
    for (int n = 0; n < 16; ++n) {
      bf16x8 vbf = *(const bf16x8*)(Vp + vrd + n * 128);
      acc0[n] = __builtin_amdgcn_mfma_f32_16x16x32_bf16(paP0, vbf, acc0[n], 0, 0, 0);
      acc1[n] = __builtin_amdgcn_mfma_f32_16x16x32_bf16(paP1, vbf, acc1[n], 0, 0, 0);
    }
  }

  // ---- epilogue: denominator reduce + 1/l redistribution, both subtiles ----
  float t0 = lp0;
  t0 += __shfl_xor(t0, 16);
  t0 += __shfl_xor(t0, 32);
  float inv0 = 1.0f / t0;
  float t1 = lp1;
  t1 += __shfl_xor(t1, 16);
  t1 += __shfl_xor(t1, 32);
  float inv1 = 1.0f / t1;
  float i00 = __shfl(inv0, lg * 4 + 0), i01 = __shfl(inv0, lg * 4 + 1);
  float i02 = __shfl(inv0, lg * 4 + 2), i03 = __shfl(inv0, lg * 4 + 3);
  float i10 = __shfl(inv1, lg * 4 + 0), i11 = __shfl(inv1, lg * 4 + 1);
  float i12 = __shfl(inv1, lg * 4 + 2), i13 = __shfl(inv1, lg * 4 + 3);
  int b = bh >> 3, h = bh & 7;
#pragma unroll
  for (int r = 0; r < 4; ++r) {
    float v0 = r == 0 ? i00 : r == 1 ? i01 : r == 2 ? i02 : i03;
    float v1 = r == 0 ? i10 : r == 1 ? i11 : r == 2 ? i12 : i13;
    int qa = q0 + lg * 4 + r;
    int qb = qa + 16;
    bf16* orow0 = AL + ((size_t)b * S_LEN + qa) * HD + h * D_HEAD;
    bf16* orow1 = AL + ((size_t)b * S_LEN + qb) * HD + h * D_HEAD;
#pragma unroll
    for (int n = 0; n < 16; ++n) {
      orow0[n * 16 + l15] = __float2bfloat16(acc0[n][r] * v0);
      orow1[n * 16 + l15] = __float2bfloat16(acc1[n][r] * v1);
    }
  }
}

extern "C" void kernel_launch(void* const* d_in, const int* in_sizes, int n_in,
                              void* d_out, int out_size, void* d_ws, size_t ws_size,
                              hipStream_t stream) {
  (void)in_sizes; (void)n_in; (void)out_size; (void)ws_size;
  const float* query  = (const float*)d_in[0];
  const float* key    = (const float*)d_in[1];
  const float* values = (const float*)d_in[2];
  const float* Wq = (const float*)d_in[3];
  const float* bq = (const float*)d_in[4];
  const float* Wk = (const float*)d_in[5];
  const float* bk = (const float*)d_in[6];
  const float* Wv = (const float*)d_in[7];
  const float* bv = (const float*)d_in[8];
  const float* Wo = (const float*)d_in[9];
  const float* bo = (const float*)d_in[10];
  float* out = (float*)d_out;

  bf16* ws = (bf16*)d_ws;
  const size_t NP = (size_t)B_SZ * H_N * S_LEN * D_HEAD;  // 16,777,216
  const size_t NW = (size_t)HD * D_HEAD;                  // 524,288
  const size_t NX = (size_t)B_SZ * S_LEN * D_HEAD;        // 2,097,152
  bf16* Qp  = ws;
  bf16* Kp  = Qp + NP;
  bf16* Vtp = Kp + NP;   // V transposed: [B*H, D, j]
  bf16* ALb = Vtp + NP;
  bf16* Wqb = ALb + NP;
  bf16* Wkb = Wqb + NW;
  bf16* Wvb = Wkb + NW;
  bf16* Wob = Wvb + NW;
  bf16* Xqb = ALb;           // X bf16 copies (dead until attn writes ALb)
  bf16* Xkb = ALb + NX;
  bf16* Xvb = ALb + 2 * NX;

  cvt_all<<<4096, 256, 0, stream>>>(Wq, Wqb, Wk, Wkb, Wv, Wvb, Wo, Wob,
                                    query, Xqb, key, Xkb, values, Xvb);

  proj3<<<dim3(1024, 3), 256, 0, stream>>>(Xqb, Xkb, Xvb, Wqb, Wkb, Wvb,
                                           bq, bk, bv, Qp, Kp, Vtp);

  attn_kernel<<<512, 256, 0, stream>>>(Qp, Kp, Vtp, ALb);

  out_gemm<<<512, 256, 0, stream>>>(ALb, Wob, bo, out);
}

// Round 18
// 230.887 us; speedup vs baseline: 1.9668x; 1.9668x over previous
//
#include <hip/hip_runtime.h>
#include <hip/hip_bf16.h>
#include <stdint.h>

#define B_SZ 4
#define H_N 8
#define S_LEN 2048
#define D_HEAD 256
#define HD 2048

typedef __attribute__((ext_vector_type(8))) short bf16x8;
typedef __attribute__((ext_vector_type(4))) float f32x4;
typedef __attribute__((ext_vector_type(4))) uint32_t u32x4;
typedef __hip_bfloat16 bf16;

typedef __attribute__((address_space(1))) const void glob_cv;
typedef __attribute__((address_space(3))) void lds_v;

__device__ __forceinline__ short f2bf(float f) {
  bf16 h = __float2bfloat16(f);
  return *reinterpret_cast<short*>(&h);
}

__device__ __forceinline__ uint32_t cvtpk(float lo, float hi) {
  uint32_t r;
  asm volatile("v_cvt_pk_bf16_f32 %0, %1, %2" : "=v"(r) : "v"(lo), "v"(hi));
  return r;
}

// ---------------- fused f32 -> bf16 converts (7 buffers, 1 launch) ----------------
__global__ __launch_bounds__(256) void cvt_all(
    const float* __restrict__ w0, bf16* __restrict__ o0,
    const float* __restrict__ w1, bf16* __restrict__ o1,
    const float* __restrict__ w2, bf16* __restrict__ o2,
    const float* __restrict__ w3, bf16* __restrict__ o3,
    const float* __restrict__ x0, bf16* __restrict__ y0,
    const float* __restrict__ x1, bf16* __restrict__ y1,
    const float* __restrict__ x2, bf16* __restrict__ y2) {
  int bid = blockIdx.x;
  const float* src; bf16* dst; int off;
  if (bid < 1024) {
    int k = bid >> 8; off = (bid & 255) * 2048;
    src = k == 0 ? w0 : k == 1 ? w1 : k == 2 ? w2 : w3;
    dst = k == 0 ? o0 : k == 1 ? o1 : k == 2 ? o2 : o3;
  } else {
    int j = bid - 1024; int k = j >> 10; off = (j & 1023) * 2048;
    src = k == 0 ? x0 : k == 1 ? x1 : x2;
    dst = k == 0 ? y0 : k == 1 ? y1 : y2;
  }
  int i = off + threadIdx.x * 8;
  float4 a = *(const float4*)(src + i);
  float4 b = *(const float4*)(src + i + 4);
  bf16x8 o;
  o[0] = f2bf(a.x); o[1] = f2bf(a.y); o[2] = f2bf(a.z); o[3] = f2bf(a.w);
  o[4] = f2bf(b.x); o[5] = f2bf(b.y); o[6] = f2bf(b.z); o[7] = f2bf(b.w);
  *reinterpret_cast<bf16x8*>(dst + i) = o;
}

// ---------------- merged projection GEMM: 3 GEMMs in one dispatch ----------------
__global__ __launch_bounds__(256, 2) void proj3(
    const bf16* __restrict__ A0, const bf16* __restrict__ A1, const bf16* __restrict__ A2,
    const bf16* __restrict__ B0, const bf16* __restrict__ B1, const bf16* __restrict__ B2,
    const float* __restrict__ c0, const float* __restrict__ c1, const float* __restrict__ c2,
    bf16* __restrict__ O0, bf16* __restrict__ O1, bf16* __restrict__ O2) {
  constexpr int HALF = 2 * 128 * 128;
  __shared__ __align__(16) char lds[2 * HALF];

  int which = blockIdx.y;
  const bf16* A = which == 0 ? A0 : which == 1 ? A1 : A2;
  const bf16* Bm = which == 0 ? B0 : which == 1 ? B1 : B2;
  const float* bias = which == 0 ? c0 : which == 1 ? c1 : c2;
  bf16* OutP = which == 0 ? O0 : which == 1 ? O1 : O2;
  float scale = which == 0 ? (1.0f / 16.0f) * 1.44269504f : 1.0f;

  int tid = threadIdx.x;
  int w = tid >> 6, l = tid & 63;
  int l15 = l & 15, lg = l >> 4;
  int wr = w >> 1, wc = w & 1;

  int bid = blockIdx.x;
  int wg = (bid & 7) * 128 + (bid >> 3);
  int mt = wg >> 4, nt = wg & 15;
  int m0 = mt * 128, n0 = nt * 128;

  const size_t K2 = 512;
  char* ldsp = (char*)lds;
  const char* Abase = (const char*)A + (size_t)m0 * K2;
  const char* Bbase = (const char*)Bm + (size_t)n0 * K2;

  auto ISSUE = [&](int buf, int kt) {
    const char* As = Abase + (size_t)kt * 128;
    const char* Bs = Bbase + (size_t)kt * 128;
    char* db = ldsp + buf * HALF;
#pragma unroll
    for (int i = 0; i < 4; ++i) {
      int c = tid + i * 256, row = c >> 3;
      __builtin_amdgcn_global_load_lds((glob_cv*)(As + (size_t)row * K2 + 16 * ((c & 7) ^ (row & 7))),
                                       (lds_v*)(db + c * 16), 16, 0, 0);
    }
#pragma unroll
    for (int i = 0; i < 4; ++i) {
      int c = tid + i * 256, row = c >> 3;
      __builtin_amdgcn_global_load_lds((glob_cv*)(Bs + (size_t)row * K2 + 16 * ((c & 7) ^ (row & 7))),
                                       (lds_v*)(db + 16384 + c * 16), 16, 0, 0);
    }
  };

  f32x4 acc[4][4];
#pragma unroll
  for (int mi = 0; mi < 4; ++mi)
#pragma unroll
    for (int ni = 0; ni < 4; ++ni) acc[mi][ni] = f32x4{0.f, 0.f, 0.f, 0.f};

  ISSUE(0, 0);
  for (int kt = 0; kt < 4; ++kt) {
    int cur = kt & 1;
    if (kt < 3) {
      ISSUE(cur ^ 1, kt + 1);
      asm volatile("s_waitcnt vmcnt(8)" ::: "memory");
    } else {
      asm volatile("s_waitcnt vmcnt(0)" ::: "memory");
    }
    __builtin_amdgcn_s_barrier();
    __builtin_amdgcn_sched_barrier(0);

    const char* bufc = ldsp + cur * HALF;
#pragma unroll
    for (int kb2 = 0; kb2 < 2; ++kb2) {
      int swz = 16 * ((kb2 * 4 + lg) ^ (l15 & 7));
      bf16x8 af[4], bfr[4];
#pragma unroll
      for (int mi = 0; mi < 4; ++mi)
        af[mi] = *(const bf16x8*)(bufc + (wr * 64 + mi * 16 + l15) * 128 + swz);
#pragma unroll
      for (int ni = 0; ni < 4; ++ni)
        bfr[ni] = *(const bf16x8*)(bufc + 16384 + (wc * 64 + ni * 16 + l15) * 128 + swz);
#pragma unroll
      for (int mi = 0; mi < 4; ++mi)
#pragma unroll
        for (int ni = 0; ni < 4; ++ni)
          acc[mi][ni] = __builtin_amdgcn_mfma_f32_16x16x32_bf16(af[mi], bfr[ni], acc[mi][ni], 0, 0, 0);
    }
    __builtin_amdgcn_sched_barrier(0);
    __builtin_amdgcn_s_barrier();
  }

  if (which == 2) {
    // V epilogue: LDS transpose -> coalesced stores into Vt[bh][d][j]
    bf16* tp = (bf16*)lds;
#pragma unroll
    for (int ni = 0; ni < 4; ++ni) {
      int colL = wc * 64 + ni * 16 + l15;
      float bv = bias[n0 + colL];
#pragma unroll
      for (int mi = 0; mi < 4; ++mi) {
        short4 pk4;
        pk4.x = f2bf(acc[mi][ni][0] + bv);
        pk4.y = f2bf(acc[mi][ni][1] + bv);
        pk4.z = f2bf(acc[mi][ni][2] + bv);
        pk4.w = f2bf(acc[mi][ni][3] + bv);
        *(short4*)(tp + colL * 136 + wr * 64 + mi * 16 + lg * 4) = pk4;
      }
    }
    __syncthreads();
    int b = m0 >> 11, h = (m0 >> 8) & 7;
    int ehi = n0 >> 8, t0 = m0 & 255;
    bf16* vb = OutP + (size_t)(b * 8 + h) * D_HEAD * S_LEN;
#pragma unroll
    for (int p = 0; p < 8; ++p) {
      int colL = p * 16 + (tid >> 4);
      int d = (n0 & 255) + colL;
      int4 v = *(const int4*)(tp + colL * 136 + (tid & 15) * 8);
      *(int4*)(vb + (size_t)d * S_LEN + ehi * 256 + t0 + (tid & 15) * 8) = v;
    }
  } else {
#pragma unroll
    for (int ni = 0; ni < 4; ++ni) {
      int col = n0 + wc * 64 + ni * 16 + l15;
      float bv = bias[col];
#pragma unroll
      for (int mi = 0; mi < 4; ++mi) {
#pragma unroll
        for (int r = 0; r < 4; ++r) {
          float v = (acc[mi][ni][r] + bv) * scale;
          int row = m0 + wr * 64 + mi * 16 + lg * 4 + r;
          int b = row >> 11;
          int h = (row >> 8) & 7;
          int d = col & 255;
          size_t off;
          if (which == 1) {
            int jj = (col >> 8) * 256 + (row & 255);            // kv-permuted K rows
            off = (((size_t)(b * 8 + h) * S_LEN) + jj) * D_HEAD + d;
          } else {
            int sp = ((row & 255) << 3) | (col >> 8);           // Q keeps sp order
            off = (((size_t)(b * 8 + h) * S_LEN) + sp) * D_HEAD + d;
          }
          OutP[off] = __float2bfloat16(v);
        }
      }
    }
  }
}

// ---------------- output GEMM: 64x64 tile, K=2048, 512 blocks ----------------
__global__ __launch_bounds__(256, 2) void out_gemm(const bf16* __restrict__ A,
                                                   const bf16* __restrict__ Bm,
                                                   const float* __restrict__ bias,
                                                   float* __restrict__ Out) {
  constexpr int HALF = 2 * 64 * 128;
  __shared__ __align__(16) char lds[2 * HALF];

  int tid = threadIdx.x;
  int w = tid >> 6, l = tid & 63;
  int l15 = l & 15, lg = l >> 4;
  int wr = w >> 1, wc = w & 1;

  int bid = blockIdx.x;
  int wg = (bid & 7) * 64 + (bid >> 3);
  int mt = wg >> 2, nt = wg & 3;
  int m0 = mt * 64, n0 = nt * 64;

  const size_t K2 = 4096;
  char* ldsp = (char*)lds;
  const char* Abase = (const char*)A + (size_t)m0 * K2;
  const char* Bbase = (const char*)Bm + (size_t)n0 * K2;

  auto ISSUE = [&](int buf, int kt) {
    const char* As = Abase + (size_t)kt * 128;
    const char* Bs = Bbase + (size_t)kt * 128;
    char* db = ldsp + buf * HALF;
#pragma unroll
    for (int i = 0; i < 2; ++i) {
      int c = tid + i * 256, row = c >> 3;
      __builtin_amdgcn_global_load_lds((glob_cv*)(As + (size_t)row * K2 + 16 * ((c & 7) ^ (row & 7))),
                                       (lds_v*)(db + c * 16), 16, 0, 0);
    }
#pragma unroll
    for (int i = 0; i < 2; ++i) {
      int c = tid + i * 256, row = c >> 3;
      __builtin_amdgcn_global_load_lds((glob_cv*)(Bs + (size_t)row * K2 + 16 * ((c & 7) ^ (row & 7))),
                                       (lds_v*)(db + 8192 + c * 16), 16, 0, 0);
    }
  };

  f32x4 acc[2][2];
#pragma unroll
  for (int mi = 0; mi < 2; ++mi)
#pragma unroll
    for (int ni = 0; ni < 2; ++ni) acc[mi][ni] = f32x4{0.f, 0.f, 0.f, 0.f};

  ISSUE(0, 0);
  for (int kt = 0; kt < 32; ++kt) {
    int cur = kt & 1;
    if (kt < 31) {
      ISSUE(cur ^ 1, kt + 1);
      asm volatile("s_waitcnt vmcnt(4)" ::: "memory");
    } else {
      asm volatile("s_waitcnt vmcnt(0)" ::: "memory");
    }
    __builtin_amdgcn_s_barrier();
    __builtin_amdgcn_sched_barrier(0);

    const char* bufc = ldsp + cur * HALF;
#pragma unroll
    for (int kb2 = 0; kb2 < 2; ++kb2) {
      int swz = 16 * ((kb2 * 4 + lg) ^ (l15 & 7));
      bf16x8 af[2], bfr[2];
#pragma unroll
      for (int mi = 0; mi < 2; ++mi)
        af[mi] = *(const bf16x8*)(bufc + (wr * 32 + mi * 16 + l15) * 128 + swz);
#pragma unroll
      for (int ni = 0; ni < 2; ++ni)
        bfr[ni] = *(const bf16x8*)(bufc + 8192 + (wc * 32 + ni * 16 + l15) * 128 + swz);
#pragma unroll
      for (int mi = 0; mi < 2; ++mi)
#pragma unroll
        for (int ni = 0; ni < 2; ++ni)
          acc[mi][ni] = __builtin_amdgcn_mfma_f32_16x16x32_bf16(af[mi], bfr[ni], acc[mi][ni], 0, 0, 0);
    }
    __builtin_amdgcn_sched_barrier(0);
    __builtin_amdgcn_s_barrier();
  }

#pragma unroll
  for (int ni = 0; ni < 2; ++ni) {
    int col = n0 + wc * 32 + ni * 16 + l15;
    float bv = bias[col];
#pragma unroll
    for (int mi = 0; mi < 2; ++mi)
#pragma unroll
      for (int r = 0; r < 4; ++r)
        Out[(size_t)(m0 + wr * 32 + mi * 16 + lg * 4 + r) * 256 + col] = acc[mi][ni][r] + bv;
  }
}

// ---------------- flash attention (best-known: R15 configuration) ----------------
// 512 blocks x 256 threads: 4 waves x 32 q-rows (2 subtiles) = QBLK 128.
// KVBLK=32 double-buffered via global_load_lds; single-barrier vmcnt(0) pipeline
// (loads issued one full iteration ahead). Swapped QK^T (lane owns q-row, 8 kv
// slots via paired-kv K staging permutation); static softmax P=exp2(sc) with
// per-lane partial denominators reduced once in the epilogue; P packs directly
// into the PV A-fragment via v_cvt_pk_bf16_f32. Each K/V fragment feeds two MFMAs.
__global__ __launch_bounds__(256, 2) void attn_kernel(const bf16* __restrict__ Qp,
                                                      const bf16* __restrict__ Kp,
                                                      const bf16* __restrict__ Vt,
                                                      bf16* __restrict__ AL) {
  __shared__ __align__(16) bf16 KVs[2 * 16384];    // 64 KB

  int tid = threadIdx.x;
  int w = tid >> 6, l = tid & 63;
  int l15 = l & 15, lg = l >> 4;
  int l31 = l & 31, hl = l >> 5;

  int bid = blockIdx.x;
  int xcd = bid & 7, j = bid >> 3;
  int bh = xcd + 8 * (j >> 4);
  int qt = j & 15;

  const bf16* Qb = Qp + (size_t)bh * S_LEN * D_HEAD;
  const bf16* Kb = Kp + (size_t)bh * S_LEN * D_HEAD;
  const bf16* Vb = Vt + (size_t)bh * (size_t)D_HEAD * S_LEN;

  int q0 = qt * 128 + w * 32;

  bf16x8 qf0[8], qf1[8];
#pragma unroll
  for (int kb = 0; kb < 8; ++kb) {
    qf0[kb] = *(const bf16x8*)(Qb + (size_t)(q0 + l15) * D_HEAD + kb * 32 + lg * 8);
    qf1[kb] = *(const bf16x8*)(Qb + (size_t)(q0 + 16 + l15) * D_HEAD + kb * 32 + lg * 8);
  }

  f32x4 acc0[16], acc1[16];
#pragma unroll
  for (int n = 0; n < 16; ++n) {
    acc0[n] = f32x4{0.f, 0.f, 0.f, 0.f};
    acc1[n] = f32x4{0.f, 0.f, 0.f, 0.f};
  }
  float lp0 = 0.f, lp1 = 0.f;   // per-lane partial denominators (disjoint kv slots)

  int kvp = 2 * (l31 & 15) + (l31 >> 4);
  const char* pK = (const char*)Kb + (size_t)kvp * 512 + (size_t)(w * 256 + hl * 16);
  const char* pV = (const char*)Vb + (size_t)l * 4096 + (size_t)((w - 2) * 32);
  int dK = w * 8192 + l * 16;
  int dV = 16384 + (w - 2) * 8192 + l * 16;
  char* ldsBase = (char*)&KVs[0];

  auto ISSUE = [&](int buf) {
    char* bb = ldsBase + buf * 32768;
    if (w < 2) {
#pragma unroll
      for (int i = 0; i < 8; ++i)
        __builtin_amdgcn_global_load_lds((glob_cv*)(pK + i * 32),
                                         (lds_v*)(bb + dK + i * 1024), 16, 0, 0);
      pK += 32 * 512;
    } else {
#pragma unroll
      for (int i = 0; i < 8; ++i)
        __builtin_amdgcn_global_load_lds((glob_cv*)(pV + (i & 3) * 262144 + (i >> 2) * 16),
                                         (lds_v*)(bb + dV + (i & 3) * 1024 + (i >> 2) * 4096), 16, 0, 0);
      pV += 64;
    }
  };

  int krd = lg * 256 + l15 * 8;
  int vrd = 8192 + lg * 2048 + l15 * 8;

  ISSUE(0);

  for (int kt = 0; kt < 64; ++kt) {
    int cur = kt & 1;
    asm volatile("s_waitcnt vmcnt(0)" ::: "memory");
    __builtin_amdgcn_s_barrier();        // tile kt landed AND tile kt-1 consumed
    __builtin_amdgcn_sched_barrier(0);
    if (kt < 63) ISSUE(cur ^ 1);

    const bf16* bufp = &KVs[cur * 16384];

    // ---- QK^T swapped: each K frag feeds both q-subtiles ----
    f32x4 s00 = f32x4{0.f,0.f,0.f,0.f}, s01 = f32x4{0.f,0.f,0.f,0.f};
    f32x4 s10 = f32x4{0.f,0.f,0.f,0.f}, s11 = f32x4{0.f,0.f,0.f,0.f};
    __builtin_amdgcn_s_setprio(1);
#pragma unroll
    for (int kb = 0; kb < 8; ++kb) {
      bf16x8 kf0 = *(const bf16x8*)(bufp + krd + kb * 1024);        // slots 0-15: kv even
      bf16x8 kf1 = *(const bf16x8*)(bufp + krd + kb * 1024 + 128);  // slots 16-31: kv odd
      s00 = __builtin_amdgcn_mfma_f32_16x16x32_bf16(kf0, qf0[kb], s00, 0, 0, 0);
      s01 = __builtin_amdgcn_mfma_f32_16x16x32_bf16(kf1, qf0[kb], s01, 0, 0, 0);
      s10 = __builtin_amdgcn_mfma_f32_16x16x32_bf16(kf0, qf1[kb], s10, 0, 0, 0);
      s11 = __builtin_amdgcn_mfma_f32_16x16x32_bf16(kf1, qf1[kb], s11, 0, 0, 0);
    }
    __builtin_amdgcn_s_setprio(0);

    // ---- static softmax both subtiles: P = exp2(sc), lane-local denominators ----
    float p00[4], p01[4], p10[4], p11[4];
#pragma unroll
    for (int r = 0; r < 4; ++r) {
      p00[r] = exp2f(s00[r]); p01[r] = exp2f(s01[r]);
      p10[r] = exp2f(s10[r]); p11[r] = exp2f(s11[r]);
    }
    lp0 += (p00[0] + p01[0]) + (p00[1] + p01[1]) + (p00[2] + p01[2]) + (p00[3] + p01[3]);
    lp1 += (p10[0] + p11[0]) + (p10[1] + p11[1]) + (p10[2] + p11[2]) + (p10[3] + p11[3]);

    union { u32x4 wq; bf16x8 v; } pu0, pu1;
    pu0.wq[0] = cvtpk(p00[0], p01[0]); pu0.wq[1] = cvtpk(p00[1], p01[1]);
    pu0.wq[2] = cvtpk(p00[2], p01[2]); pu0.wq[3] = cvtpk(p00[3], p01[3]);
    pu1.wq[0] = cvtpk(p10[0], p11[0]); pu1.wq[1] = cvtpk(p10[1], p11[1]);
    pu1.wq[2] = cvtpk(p10[2], p11[2]); pu1.wq[3] = cvtpk(p10[3], p11[3]);
    bf16x8 pa0 = pu0.v, pa1 = pu1.v;

    // ---- PV: each V frag feeds both q-subtiles ----
    __builtin_amdgcn_s_setprio(1);
#pragma unroll
    for (int n = 0; n < 16; ++n) {
      bf16x8 vbf = *(const bf16x8*)(bufp + vrd + n * 128);
      acc0[n] = __builtin_amdgcn_mfma_f32_16x16x32_bf16(pa0, vbf, acc0[n], 0, 0, 0);
      acc1[n] = __builtin_amdgcn_mfma_f32_16x16x32_bf16(pa1, vbf, acc1[n], 0, 0, 0);
    }
    __builtin_amdgcn_s_setprio(0);
  }

  // ---- epilogue: denominator reduce + 1/l redistribution, both subtiles ----
  float t0 = lp0;
  t0 += __shfl_xor(t0, 16);
  t0 += __shfl_xor(t0, 32);
  float inv0 = 1.0f / t0;          // lane q = q0 + l15
  float t1 = lp1;
  t1 += __shfl_xor(t1, 16);
  t1 += __shfl_xor(t1, 32);
  float inv1 = 1.0f / t1;          // lane q = q0 + 16 + l15
  float i00 = __shfl(inv0, lg * 4 + 0), i01 = __shfl(inv0, lg * 4 + 1);
  float i02 = __shfl(inv0, lg * 4 + 2), i03 = __shfl(inv0, lg * 4 + 3);
  float i10 = __shfl(inv1, lg * 4 + 0), i11 = __shfl(inv1, lg * 4 + 1);
  float i12 = __shfl(inv1, lg * 4 + 2), i13 = __shfl(inv1, lg * 4 + 3);
  int b = bh >> 3, h = bh & 7;
#pragma unroll
  for (int r = 0; r < 4; ++r) {
    float v0 = r == 0 ? i00 : r == 1 ? i01 : r == 2 ? i02 : i03;
    float v1 = r == 0 ? i10 : r == 1 ? i11 : r == 2 ? i12 : i13;
    int qa = q0 + lg * 4 + r;
    int qb = qa + 16;
    bf16* orow0 = AL + ((size_t)b * S_LEN + qa) * HD + h * D_HEAD;
    bf16* orow1 = AL + ((size_t)b * S_LEN + qb) * HD + h * D_HEAD;
#pragma unroll
    for (int n = 0; n < 16; ++n) {
      orow0[n * 16 + l15] = __float2bfloat16(acc0[n][r] * v0);
      orow1[n * 16 + l15] = __float2bfloat16(acc1[n][r] * v1);
    }
  }
}

extern "C" void kernel_launch(void* const* d_in, const int* in_sizes, int n_in,
                              void* d_out, int out_size, void* d_ws, size_t ws_size,
                              hipStream_t stream) {
  (void)in_sizes; (void)n_in; (void)out_size; (void)ws_size;
  const float* query  = (const float*)d_in[0];
  const float* key    = (const float*)d_in[1];
  const float* values = (const float*)d_in[2];
  const float* Wq = (const float*)d_in[3];
  const float* bq = (const float*)d_in[4];
  const float* Wk = (const float*)d_in[5];
  const float* bk = (const float*)d_in[6];
  const float* Wv = (const float*)d_in[7];
  const float* bv = (const float*)d_in[8];
  const float* Wo = (const float*)d_in[9];
  const float* bo = (const float*)d_in[10];
  float* out = (float*)d_out;

  bf16* ws = (bf16*)d_ws;
  const size_t NP = (size_t)B_SZ * H_N * S_LEN * D_HEAD;  // 16,777,216
  const size_t NW = (size_t)HD * D_HEAD;                  // 524,288
  const size_t NX = (size_t)B_SZ * S_LEN * D_HEAD;        // 2,097,152
  bf16* Qp  = ws;
  bf16* Kp  = Qp + NP;
  bf16* Vtp = Kp + NP;   // V transposed: [B*H, D, j]
  bf16* ALb = Vtp + NP;
  bf16* Wqb = ALb + NP;
  bf16* Wkb = Wqb + NW;
  bf16* Wvb = Wkb + NW;
  bf16* Wob = Wvb + NW;
  bf16* Xqb = ALb;           // X bf16 copies (dead until attn writes ALb)
  bf16* Xkb = ALb + NX;
  bf16* Xvb = ALb + 2 * NX;

  cvt_all<<<4096, 256, 0, stream>>>(Wq, Wqb, Wk, Wkb, Wv, Wvb, Wo, Wob,
                                    query, Xqb, key, Xkb, values, Xvb);

  proj3<<<dim3(1024, 3), 256, 0, stream>>>(Xqb, Xkb, Xvb, Wqb, Wkb, Wvb,
                                           bq, bk, bv, Qp, Kp, Vtp);

  attn_kernel<<<512, 256, 0, stream>>>(Qp, Kp, Vtp, ALb);

  out_gemm<<<512, 256, 0, stream>>>(ALb, Wob, bo, out);
}